// Round 1
// baseline (1656.594 us; speedup 1.0000x reference)
//
#include <hip/hip_runtime.h>
#include <hip/hip_bf16.h>

typedef unsigned short u16;
using short8 = __attribute__((ext_vector_type(8))) short;
using half8  = __attribute__((ext_vector_type(8))) _Float16;
using f32x4  = __attribute__((ext_vector_type(4))) float;

__device__ __forceinline__ u16 f2bf(float f) {
    unsigned int u = __float_as_uint(f);
    u += 0x7FFFu + ((u >> 16) & 1u);   // RNE
    return (u16)(u >> 16);
}
__device__ __forceinline__ float bf2f(u16 h) {
    return __uint_as_float(((unsigned int)h) << 16);
}

// ---------------- weight prep: HWIO -> [kk][n][ci], split bf16 hi/lo ----------------
__global__ __launch_bounds__(256) void wprep_split_kernel(const float* __restrict__ src,
                                                          u16* __restrict__ hi, u16* __restrict__ lo) {
    int idx = blockIdx.x * 256 + threadIdx.x;          // 16*256*256
    int ci = idx & 255, n = (idx >> 8) & 255, kk = idx >> 16;
    float v = src[(kk * 256 + ci) * 256 + n];
    u16 h = f2bf(v);
    hi[idx] = h;
    lo[idx] = f2bf(v - bf2f(h));
}

// ---------------- weight prep: HWIO -> [kk][n][ci] fp16 ----------------
__global__ __launch_bounds__(256) void wprep_f16_kernel(const float* __restrict__ src,
                                                        _Float16* __restrict__ dst) {
    int idx = blockIdx.x * 256 + threadIdx.x;
    int ci = idx & 255, n = (idx >> 8) & 255, kk = idx >> 16;
    dst[idx] = (_Float16)src[(kk * 256 + ci) * 256 + n];
}

// ---------------- conv1 (1->256, 4x4 SAME) + ReLU + maxpool2x2, split bf16 out ----------------
__global__ __launch_bounds__(256) void conv1_pool_kernel(const float* __restrict__ x,
                                                         const float* __restrict__ w,
                                                         const float* __restrict__ bias,
                                                         u16* __restrict__ hi, u16* __restrict__ lo) {
    __shared__ float xs[5][5];
    const int blk = blockIdx.x;                         // b*196 + py*14 + px
    const int px = blk % 14, py = (blk / 14) % 14, b = blk / 196;
    const int t = threadIdx.x;
    if (t < 25) {
        int r = t / 5, c = t % 5;
        int gy = 2 * py - 1 + r, gx = 2 * px - 1 + c;
        xs[r][c] = (gy >= 0 && gy < 28 && gx >= 0 && gx < 28) ? x[(b * 28 + gy) * 28 + gx] : 0.f;
    }
    __syncthreads();
    float wr[16];
#pragma unroll
    for (int k = 0; k < 16; ++k) wr[k] = w[k * 256 + t];
    const float bs = bias[t];
    float m = -1e30f;
#pragma unroll
    for (int dy = 0; dy < 2; ++dy)
#pragma unroll
        for (int dx = 0; dx < 2; ++dx) {
            float acc = bs;
#pragma unroll
            for (int ky = 0; ky < 4; ++ky)
#pragma unroll
                for (int kx = 0; kx < 4; ++kx)
                    acc += xs[dy + ky][dx + kx] * wr[ky * 4 + kx];
            m = fmaxf(m, acc);
        }
    m = fmaxf(m, 0.f);
    u16 h = f2bf(m);
    int o = blk * 256 + t;
    hi[o] = h;
    lo[o] = f2bf(m - bf2f(h));
}

// ---------------- conv2: 16-tap implicit GEMM, split-bf16 3-pass MFMA, ReLU, f32 out ----------------
// M = 256*14*14 = 50176, N = 256, K = 16 x 256.
__global__ __launch_bounds__(256) void conv2_split_kernel(const u16* __restrict__ Ih, const u16* __restrict__ Il,
                                                          const u16* __restrict__ Wh, const u16* __restrict__ Wl,
                                                          const float* __restrict__ bias, float* __restrict__ out) {
    const int HW = 196, W = 14;
    __shared__ __align__(16) short Ah[64][72], Al[64][72], Bh[64][72], Bl[64][72];
    const int t = threadIdx.x;
    const int m0 = blockIdx.x * 64, n0 = blockIdx.y * 64;
    const int seg = t & 7, r0 = t >> 3;
    int b0, y0, x0, b1, y1, x1;
    { int m = m0 + r0;      b0 = m / HW; int rem = m % HW; y0 = rem / W; x0 = rem % W; }
    { int m = m0 + r0 + 32; b1 = m / HW; int rem = m % HW; y1 = rem / W; x1 = rem % W; }
    const int lane = t & 63, wid = t >> 6;
    const int wm = wid >> 1, wn = wid & 1;
    const int l16 = lane & 15, l4 = lane >> 4;
    f32x4 acc[2][2] = {};
    const int4 zz = make_int4(0, 0, 0, 0);

    for (int kk = 0; kk < 16; ++kk) {
        const int ky = kk >> 2, kx = kk & 3;
        int aoff0 = -1, aoff1 = -1;
        { int iy = y0 + ky - 1, ix = x0 + kx - 1;
          if ((unsigned)iy < 14u && (unsigned)ix < 14u) aoff0 = (((b0 * 14 + iy) * 14 + ix) << 8); }
        { int iy = y1 + ky - 1, ix = x1 + kx - 1;
          if ((unsigned)iy < 14u && (unsigned)ix < 14u) aoff1 = (((b1 * 14 + iy) * 14 + ix) << 8); }
        const size_t wrow0 = ((size_t)(kk * 256 + n0 + r0)) << 8;
        const size_t wrow1 = wrow0 + (32u << 8);

        for (int c4 = 0; c4 < 4; ++c4) {
            const int ci = c4 * 64 + seg * 8;
            __syncthreads();
            *(int4*)&Ah[r0][seg * 8]      = (aoff0 >= 0) ? *(const int4*)(Ih + aoff0 + ci) : zz;
            *(int4*)&Al[r0][seg * 8]      = (aoff0 >= 0) ? *(const int4*)(Il + aoff0 + ci) : zz;
            *(int4*)&Ah[r0 + 32][seg * 8] = (aoff1 >= 0) ? *(const int4*)(Ih + aoff1 + ci) : zz;
            *(int4*)&Al[r0 + 32][seg * 8] = (aoff1 >= 0) ? *(const int4*)(Il + aoff1 + ci) : zz;
            *(int4*)&Bh[r0][seg * 8]      = *(const int4*)(Wh + wrow0 + ci);
            *(int4*)&Bl[r0][seg * 8]      = *(const int4*)(Wl + wrow0 + ci);
            *(int4*)&Bh[r0 + 32][seg * 8] = *(const int4*)(Wh + wrow1 + ci);
            *(int4*)&Bl[r0 + 32][seg * 8] = *(const int4*)(Wl + wrow1 + ci);
            __syncthreads();
#pragma unroll
            for (int ks = 0; ks < 2; ++ks) {
                short8 ah[2], al[2], bh[2], bl[2];
#pragma unroll
                for (int mi = 0; mi < 2; ++mi) {
                    ah[mi] = *(const short8*)&Ah[wm * 32 + mi * 16 + l16][ks * 32 + l4 * 8];
                    al[mi] = *(const short8*)&Al[wm * 32 + mi * 16 + l16][ks * 32 + l4 * 8];
                }
#pragma unroll
                for (int ni = 0; ni < 2; ++ni) {
                    bh[ni] = *(const short8*)&Bh[wn * 32 + ni * 16 + l16][ks * 32 + l4 * 8];
                    bl[ni] = *(const short8*)&Bl[wn * 32 + ni * 16 + l16][ks * 32 + l4 * 8];
                }
#pragma unroll
                for (int mi = 0; mi < 2; ++mi)
#pragma unroll
                    for (int ni = 0; ni < 2; ++ni) {
                        acc[mi][ni] = __builtin_amdgcn_mfma_f32_16x16x32_bf16(ah[mi], bh[ni], acc[mi][ni], 0, 0, 0);
                        acc[mi][ni] = __builtin_amdgcn_mfma_f32_16x16x32_bf16(ah[mi], bl[ni], acc[mi][ni], 0, 0, 0);
                        acc[mi][ni] = __builtin_amdgcn_mfma_f32_16x16x32_bf16(al[mi], bh[ni], acc[mi][ni], 0, 0, 0);
                    }
            }
        }
    }
#pragma unroll
    for (int mi = 0; mi < 2; ++mi)
#pragma unroll
        for (int ni = 0; ni < 2; ++ni) {
            const int mrow = m0 + wm * 32 + mi * 16 + l4 * 4;
            const int ncol = n0 + wn * 32 + ni * 16 + l16;
            const float bv = bias[ncol];
#pragma unroll
            for (int r = 0; r < 4; ++r) {
                float v = fmaxf(acc[mi][ni][r] + bv, 0.f);
                out[(size_t)(mrow + r) * 256 + ncol] = v;
            }
        }
}

// ---------------- deconv1 (fused 2x upsample): fp16 MFMA, ReLU, fp16 out ----------------
// M = 512*14*14 = 100352, N = 256; phys input is [512][7][7][256] fp16.
__global__ __launch_bounds__(256) void deconv1_f16_kernel(const _Float16* __restrict__ I,
                                                          const _Float16* __restrict__ WT,
                                                          const float* __restrict__ bias,
                                                          _Float16* __restrict__ out) {
    const int HW = 196, W = 14;
    __shared__ __align__(16) _Float16 As[64][72], Bs[64][72];
    const int t = threadIdx.x;
    const int m0 = blockIdx.x * 64, n0 = blockIdx.y * 64;
    const int seg = t & 7, r0 = t >> 3;
    int b0, y0, x0, b1, y1, x1;
    { int m = m0 + r0;      b0 = m / HW; int rem = m % HW; y0 = rem / W; x0 = rem % W; }
    { int m = m0 + r0 + 32; b1 = m / HW; int rem = m % HW; y1 = rem / W; x1 = rem % W; }
    const int lane = t & 63, wid = t >> 6;
    const int wm = wid >> 1, wn = wid & 1;
    const int l16 = lane & 15, l4 = lane >> 4;
    f32x4 acc[2][2] = {};
    const int4 zz = make_int4(0, 0, 0, 0);

    for (int kk = 0; kk < 16; ++kk) {
        const int ky = kk >> 2, kx = kk & 3;
        int aoff0 = -1, aoff1 = -1;
        { int iy = y0 + ky - 1, ix = x0 + kx - 1;
          if ((unsigned)iy < 14u && (unsigned)ix < 14u) aoff0 = (((b0 * 7 + (iy >> 1)) * 7 + (ix >> 1)) << 8); }
        { int iy = y1 + ky - 1, ix = x1 + kx - 1;
          if ((unsigned)iy < 14u && (unsigned)ix < 14u) aoff1 = (((b1 * 7 + (iy >> 1)) * 7 + (ix >> 1)) << 8); }
        const size_t wrow0 = ((size_t)(kk * 256 + n0 + r0)) << 8;
        const size_t wrow1 = wrow0 + (32u << 8);

        for (int c4 = 0; c4 < 4; ++c4) {
            const int ci = c4 * 64 + seg * 8;
            __syncthreads();
            *(int4*)&As[r0][seg * 8]      = (aoff0 >= 0) ? *(const int4*)(I + aoff0 + ci) : zz;
            *(int4*)&As[r0 + 32][seg * 8] = (aoff1 >= 0) ? *(const int4*)(I + aoff1 + ci) : zz;
            *(int4*)&Bs[r0][seg * 8]      = *(const int4*)(WT + wrow0 + ci);
            *(int4*)&Bs[r0 + 32][seg * 8] = *(const int4*)(WT + wrow1 + ci);
            __syncthreads();
#pragma unroll
            for (int ks = 0; ks < 2; ++ks) {
                half8 a0 = *(const half8*)&As[wm * 32 + l16][ks * 32 + l4 * 8];
                half8 a1 = *(const half8*)&As[wm * 32 + 16 + l16][ks * 32 + l4 * 8];
                half8 q0 = *(const half8*)&Bs[wn * 32 + l16][ks * 32 + l4 * 8];
                half8 q1 = *(const half8*)&Bs[wn * 32 + 16 + l16][ks * 32 + l4 * 8];
                acc[0][0] = __builtin_amdgcn_mfma_f32_16x16x32_f16(a0, q0, acc[0][0], 0, 0, 0);
                acc[0][1] = __builtin_amdgcn_mfma_f32_16x16x32_f16(a0, q1, acc[0][1], 0, 0, 0);
                acc[1][0] = __builtin_amdgcn_mfma_f32_16x16x32_f16(a1, q0, acc[1][0], 0, 0, 0);
                acc[1][1] = __builtin_amdgcn_mfma_f32_16x16x32_f16(a1, q1, acc[1][1], 0, 0, 0);
            }
        }
    }
#pragma unroll
    for (int mi = 0; mi < 2; ++mi)
#pragma unroll
        for (int ni = 0; ni < 2; ++ni) {
            const int mrow = m0 + wm * 32 + mi * 16 + l4 * 4;
            const int ncol = n0 + wn * 32 + ni * 16 + l16;
            const float bv = bias[ncol];
#pragma unroll
            for (int r = 0; r < 4; ++r) {
                float v = fmaxf(acc[mi][ni][r] + bv, 0.f);
                out[(size_t)(mrow + r) * 256 + ncol] = (_Float16)v;
            }
        }
}

// ---------------- maxpool 2x2 on h2 (f32) -> h2p (f32, flattened NHWC) ----------------
__global__ __launch_bounds__(256) void pool2_kernel(const float* __restrict__ h2, float* __restrict__ h2p) {
    int idx = blockIdx.x * 256 + threadIdx.x;           // 256*49*256
    int c = idx & 255;
    int rest = idx >> 8;
    int px = rest % 7, py = (rest / 7) % 7, b = rest / 49;
    const float* base = h2 + (((size_t)(b * 14 + 2 * py)) * 14 + 2 * px) * 256 + c;
    float v = fmaxf(fmaxf(base[0], base[256]), fmaxf(base[14 * 256], base[14 * 256 + 256]));
    h2p[idx] = v;
}

// ---------------- encoder linear: [256,12544] @ [12544,64] + b -> zcat rows 0..255 ----------------
__global__ __launch_bounds__(256) void enc_kernel(const float* __restrict__ h2p, const float* __restrict__ ew,
                                                  const float* __restrict__ eb, float* __restrict__ zcat) {
    __shared__ float arow[12544];
    __shared__ float part[256];
    const int b = blockIdx.x, t = threadIdx.x;
    const float* src = h2p + (size_t)b * 12544;
    for (int i = t; i < 12544; i += 256) arow[i] = src[i];
    __syncthreads();
    const int n = t & 63, chunk = t >> 6;
    float acc = 0.f;
    const int k0 = chunk * 3136;
    for (int k = k0; k < k0 + 3136; ++k) acc += arow[k] * ew[k * 64 + n];
    part[t] = acc;
    __syncthreads();
    if (t < 64) zcat[b * 64 + t] = part[t] + part[t + 64] + part[t + 128] + part[t + 192] + eb[t];
}

// ---------------- SOM: nearest embedding (argmin, first-index ties) -> zcat rows 256..511 ----------------
__global__ __launch_bounds__(256) void som_kernel(const float* __restrict__ emb, float* __restrict__ zcat) {
    __shared__ float zrow[64];
    __shared__ float sd[256];
    __shared__ int si[256];
    const int b = blockIdx.x, t = threadIdx.x;
    if (t < 64) zrow[t] = zcat[b * 64 + t];
    __syncthreads();
    float acc = 0.f;
    const float* e = emb + t * 64;
    for (int d = 0; d < 64; ++d) { float df = zrow[d] - e[d]; acc += df * df; }
    sd[t] = acc; si[t] = t;
    __syncthreads();
    for (int off = 128; off >= 1; off >>= 1) {
        if (t < off) {
            float d2 = sd[t + off]; int i2 = si[t + off];
            if (d2 < sd[t] || (d2 == sd[t] && i2 < si[t])) { sd[t] = d2; si[t] = i2; }
        }
        __syncthreads();
    }
    const int k = si[0];
    if (t < 64) zcat[(256 + b) * 64 + t] = emb[k * 64 + t];
}

// ---------------- decoder linear: [512,64] @ [64,12544] + b -> dech fp16 ----------------
__global__ __launch_bounds__(256) void dec_kernel(const float* __restrict__ zcat, const float* __restrict__ dw,
                                                  const float* __restrict__ db, _Float16* __restrict__ dech) {
    __shared__ float z[8][64];
    const int t = threadIdx.x;
    const int bg = blockIdx.x / 49;                     // group of 8 batch rows
    const int nc = blockIdx.x % 49;
    for (int i = t; i < 512; i += 256) z[i >> 6][i & 63] = zcat[bg * 512 + i];
    __syncthreads();
    const int n = nc * 256 + t;
    const float bv = db[n];
    float acc[8];
#pragma unroll
    for (int j = 0; j < 8; ++j) acc[j] = bv;
    for (int k = 0; k < 64; ++k) {
        float wv = dw[(size_t)k * 12544 + n];
#pragma unroll
        for (int j = 0; j < 8; ++j) acc[j] += z[j][k] * wv;
    }
#pragma unroll
    for (int j = 0; j < 8; ++j) dech[((size_t)(bg * 8 + j)) * 12544 + n] = (_Float16)acc[j];
}

// ---------------- deconv2 (fused upsample, 256->1) + sigmoid -> d_out ----------------
__global__ __launch_bounds__(256) void deconv2_kernel(const _Float16* __restrict__ d1, const float* __restrict__ w,
                                                      const float* __restrict__ bias, float* __restrict__ out) {
    __shared__ float wl[4096];
    const int t = threadIdx.x;
    for (int i = t; i < 4096; i += 256) wl[i] = w[i];
    __syncthreads();
    const int wid = t >> 6, lane = t & 63;
    const int p = blockIdx.x * 4 + wid;                 // 512*28*28 pixels
    const int x = p % 28, y = (p / 28) % 28, b = p / 784;
    const int ci0 = lane * 4;
    float acc = 0.f;
#pragma unroll
    for (int kk = 0; kk < 16; ++kk) {
        const int ky = kk >> 2, kx = kk & 3;
        const int iy = y + ky - 1, ix = x + kx - 1;
        if ((unsigned)iy < 28u && (unsigned)ix < 28u) {
            const _Float16* src = d1 + (((size_t)((b * 14 + (iy >> 1)) * 14 + (ix >> 1))) << 8) + ci0;
            const float* wp = wl + kk * 256 + ci0;
            acc += (float)src[0] * wp[0] + (float)src[1] * wp[1] + (float)src[2] * wp[2] + (float)src[3] * wp[3];
        }
    }
#pragma unroll
    for (int off = 32; off; off >>= 1) acc += __shfl_xor(acc, off);
    if (lane == 0) out[p] = 1.f / (1.f + expf(-(acc + bias[0])));
}

extern "C" void kernel_launch(void* const* d_in, const int* in_sizes, int n_in,
                              void* d_out, int out_size, void* d_ws, size_t ws_size,
                              hipStream_t stream) {
    const float* x    = (const float*)d_in[0];
    const float* c1w  = (const float*)d_in[1];
    const float* c1b  = (const float*)d_in[2];
    const float* c2w  = (const float*)d_in[3];
    const float* c2b  = (const float*)d_in[4];
    const float* ew   = (const float*)d_in[5];
    const float* eb   = (const float*)d_in[6];
    const float* emb  = (const float*)d_in[7];
    const float* dw   = (const float*)d_in[8];
    const float* db   = (const float*)d_in[9];
    const float* dc1w = (const float*)d_in[10];
    const float* dc1b = (const float*)d_in[11];
    const float* dc2w = (const float*)d_in[12];
    const float* dc2b = (const float*)d_in[13];
    float* out = (float*)d_out;

    char* ws = (char*)d_ws;
    size_t off = 0;
    auto alloc = [&](size_t bytes) { size_t o = off; off += (bytes + 255) & ~(size_t)255; return o; };

    u16*      h1p_hi = (u16*)(ws + alloc((size_t)256 * 196 * 256 * 2));
    u16*      h1p_lo = (u16*)(ws + alloc((size_t)256 * 196 * 256 * 2));
    u16*      w2T_hi = (u16*)(ws + alloc((size_t)16 * 256 * 256 * 2));
    u16*      w2T_lo = (u16*)(ws + alloc((size_t)16 * 256 * 256 * 2));
    float*    h2     = (float*)(ws + alloc((size_t)256 * 196 * 256 * 4));
    float*    h2p    = (float*)(ws + alloc((size_t)256 * 49 * 256 * 4));
    float*    zcat   = (float*)(ws + alloc((size_t)512 * 64 * 4));
    _Float16* dech   = (_Float16*)(ws + alloc((size_t)512 * 49 * 256 * 2));
    _Float16* dw1T   = (_Float16*)(ws + alloc((size_t)16 * 256 * 256 * 2));
    _Float16* d1     = (_Float16*)(ws + alloc((size_t)512 * 196 * 256 * 2));

    wprep_split_kernel<<<4096, 256, 0, stream>>>(c2w, w2T_hi, w2T_lo);
    wprep_f16_kernel<<<4096, 256, 0, stream>>>(dc1w, dw1T);
    conv1_pool_kernel<<<50176, 256, 0, stream>>>(x, c1w, c1b, h1p_hi, h1p_lo);
    conv2_split_kernel<<<dim3(784, 4), 256, 0, stream>>>(h1p_hi, h1p_lo, w2T_hi, w2T_lo, c2b, h2);
    pool2_kernel<<<12544, 256, 0, stream>>>(h2, h2p);
    enc_kernel<<<256, 256, 0, stream>>>(h2p, ew, eb, zcat);
    som_kernel<<<256, 256, 0, stream>>>(emb, zcat);
    dec_kernel<<<3136, 256, 0, stream>>>(zcat, dw, db, dech);
    deconv1_f16_kernel<<<dim3(1568, 4), 256, 0, stream>>>(dech, dw1T, dc1b, d1);
    deconv2_kernel<<<100352, 256, 0, stream>>>(d1, dc2w, dc2b, out);
}

// Round 2
// 891.264 us; speedup vs baseline: 1.8587x; 1.8587x over previous
//
#include <hip/hip_runtime.h>
#include <hip/hip_bf16.h>

typedef unsigned short u16;
using short8 = __attribute__((ext_vector_type(8))) short;
using half8  = __attribute__((ext_vector_type(8))) _Float16;
using half4  = __attribute__((ext_vector_type(4))) _Float16;
using half2v = __attribute__((ext_vector_type(2))) _Float16;
using f32x4  = __attribute__((ext_vector_type(4))) float;

__device__ __forceinline__ u16 f2bf(float f) {
    unsigned int u = __float_as_uint(f);
    u += 0x7FFFu + ((u >> 16) & 1u);   // RNE
    return (u16)(u >> 16);
}
__device__ __forceinline__ float bf2f(u16 h) {
    return __uint_as_float(((unsigned int)h) << 16);
}

__device__ __forceinline__ void gl_lds16(const void* g, void* l) {
    __builtin_amdgcn_global_load_lds((const __attribute__((address_space(1))) void*)g,
                                     (__attribute__((address_space(3))) void*)l, 16, 0, 0);
}

// ---------------- weight prep: HWIO -> [kk][n][ci], split bf16 hi/lo ----------------
__global__ __launch_bounds__(256) void wprep_split_kernel(const float* __restrict__ src,
                                                          u16* __restrict__ hi, u16* __restrict__ lo) {
    int idx = blockIdx.x * 256 + threadIdx.x;          // 16*256*256
    int ci = idx & 255, n = (idx >> 8) & 255, kk = idx >> 16;
    float v = src[(kk * 256 + ci) * 256 + n];
    u16 h = f2bf(v);
    hi[idx] = h;
    lo[idx] = f2bf(v - bf2f(h));
}

// ---------------- weight prep: HWIO -> [kk][n][ci] fp16 ----------------
__global__ __launch_bounds__(256) void wprep_f16_kernel(const float* __restrict__ src,
                                                        _Float16* __restrict__ dst) {
    int idx = blockIdx.x * 256 + threadIdx.x;
    int ci = idx & 255, n = (idx >> 8) & 255, kk = idx >> 16;
    dst[idx] = (_Float16)src[(kk * 256 + ci) * 256 + n];
}

// ---------------- weight prep: deconv2 w (4,4,256,1) -> fp16 flat ----------------
__global__ __launch_bounds__(256) void wprep_c2_kernel(const float* __restrict__ src, _Float16* __restrict__ dst) {
    int idx = blockIdx.x * 256 + threadIdx.x;          // 4096
    dst[idx] = (_Float16)src[idx];
}

// ---------------- conv1 (1->256, 4x4 SAME) + ReLU + maxpool2x2, split bf16 out ----------------
__global__ __launch_bounds__(256) void conv1_pool_kernel(const float* __restrict__ x,
                                                         const float* __restrict__ w,
                                                         const float* __restrict__ bias,
                                                         u16* __restrict__ hi, u16* __restrict__ lo) {
    __shared__ float xs[5][5];
    const int blk = blockIdx.x;                         // b*196 + py*14 + px
    const int px = blk % 14, py = (blk / 14) % 14, b = blk / 196;
    const int t = threadIdx.x;
    if (t < 25) {
        int r = t / 5, c = t % 5;
        int gy = 2 * py - 1 + r, gx = 2 * px - 1 + c;
        xs[r][c] = (gy >= 0 && gy < 28 && gx >= 0 && gx < 28) ? x[(b * 28 + gy) * 28 + gx] : 0.f;
    }
    __syncthreads();
    float wr[16];
#pragma unroll
    for (int k = 0; k < 16; ++k) wr[k] = w[k * 256 + t];
    const float bs = bias[t];
    float m = -1e30f;
#pragma unroll
    for (int dy = 0; dy < 2; ++dy)
#pragma unroll
        for (int dx = 0; dx < 2; ++dx) {
            float acc = bs;
#pragma unroll
            for (int ky = 0; ky < 4; ++ky)
#pragma unroll
                for (int kx = 0; kx < 4; ++kx)
                    acc += xs[dy + ky][dx + kx] * wr[ky * 4 + kx];
            m = fmaxf(m, acc);
        }
    m = fmaxf(m, 0.f);
    u16 h = f2bf(m);
    int o = blk * 256 + t;
    hi[o] = h;
    lo[o] = f2bf(m - bf2f(h));
}

// ---------------- conv2 v2: 128x128 tile, global_load_lds + XOR-swizzle, split-bf16 3-pass ----------------
// M = 50176, N = 256, K = 16 x 256.  Grid (392, 2), 256 threads (4 waves, each owns 64x64).
__global__ __launch_bounds__(256, 2) void conv2_split_v2(const u16* __restrict__ Ih, const u16* __restrict__ Il,
                                                         const u16* __restrict__ Wh, const u16* __restrict__ Wl,
                                                         const u16* __restrict__ zg,
                                                         const float* __restrict__ bias, float* __restrict__ out) {
    __shared__ __align__(16) short lds[32768];          // AH 0, AL 8192, BH 16384, BL 24576 (64 KiB)
    const int AL = 8192, BH = 16384, BL = 24576;
    const int t = threadIdx.x, lane = t & 63, w = t >> 6;
    const int wm = w >> 1, wn = w & 1;
    const int l16 = lane & 15, l4 = lane >> 4;
    const int m0 = blockIdx.x * 128, n0 = blockIdx.y * 128;
    // staging geometry: wave w stages rows 32w..32w+31 of each array; instr j covers 8 rows.
    const int rl = lane >> 3;                           // row within 8-group (== row&7)
    const int chS = (((lane & 7) ^ rl)) << 3;           // source chunk offset in shorts (16B units)
    int ay[4], ax[4], ab[4], wb[4], aoff[4];
    bool av[4];
#pragma unroll
    for (int j = 0; j < 4; ++j) {
        const int r = w * 32 + j * 8 + rl;
        const int gm = m0 + r;
        const int b = gm / 196, rem = gm % 196;
        ay[j] = rem / 14; ax[j] = rem % 14; ab[j] = b * 196;
        wb[j] = (n0 + r) << 8;
    }
    f32x4 acc[4][4] = {};

    for (int kt = 0; kt < 64; ++kt) {
        const int kk = kt >> 2;
        if ((kt & 3) == 0) {
            const int ky = kk >> 2, kx = kk & 3;
#pragma unroll
            for (int j = 0; j < 4; ++j) {
                const int iy = ay[j] + ky - 1, ix = ax[j] + kx - 1;
                av[j] = ((unsigned)iy < 14u) && ((unsigned)ix < 14u);
                aoff[j] = (ab[j] + iy * 14 + ix) << 8;
            }
        }
        const int kc = (kt & 3) << 6;
        __syncthreads();
#pragma unroll
        for (int j = 0; j < 4; ++j) {
            const int rowb = (w * 32 + j * 8) << 6;     // row*64 shorts
            const u16* gh = av[j] ? (Ih + aoff[j] + kc + chS) : zg;
            const u16* gl = av[j] ? (Il + aoff[j] + kc + chS) : zg;
            gl_lds16(gh, lds + rowb);
            gl_lds16(gl, lds + AL + rowb);
            const int woff = (kk << 16) + wb[j] + kc + chS;
            gl_lds16(Wh + woff, lds + BH + rowb);
            gl_lds16(Wl + woff, lds + BL + rowb);
        }
        __syncthreads();
#pragma unroll
        for (int ks = 0; ks < 2; ++ks) {
            short8 bhf[4], blf[4];
#pragma unroll
            for (int ni = 0; ni < 4; ++ni) {
                const int row = wn * 64 + ni * 16 + l16;
                const int p = (ks * 4 + l4) ^ (row & 7);
                const int off = (row << 6) + (p << 3);
                bhf[ni] = *(const short8*)&lds[BH + off];
                blf[ni] = *(const short8*)&lds[BL + off];
            }
#pragma unroll
            for (int mi = 0; mi < 4; ++mi) {
                const int row = wm * 64 + mi * 16 + l16;
                const int p = (ks * 4 + l4) ^ (row & 7);
                const int off = (row << 6) + (p << 3);
                const short8 ah = *(const short8*)&lds[off];
                const short8 al = *(const short8*)&lds[AL + off];
#pragma unroll
                for (int ni = 0; ni < 4; ++ni) {
                    acc[mi][ni] = __builtin_amdgcn_mfma_f32_16x16x32_bf16(ah, bhf[ni], acc[mi][ni], 0, 0, 0);
                    acc[mi][ni] = __builtin_amdgcn_mfma_f32_16x16x32_bf16(ah, blf[ni], acc[mi][ni], 0, 0, 0);
                    acc[mi][ni] = __builtin_amdgcn_mfma_f32_16x16x32_bf16(al, bhf[ni], acc[mi][ni], 0, 0, 0);
                }
            }
        }
    }
#pragma unroll
    for (int ni = 0; ni < 4; ++ni) {
        const int col = n0 + wn * 64 + ni * 16 + l16;
        const float bv = bias[col];
#pragma unroll
        for (int mi = 0; mi < 4; ++mi) {
            const int mrow = m0 + wm * 64 + mi * 16 + l4 * 4;
#pragma unroll
            for (int r = 0; r < 4; ++r)
                out[(size_t)(mrow + r) * 256 + col] = fmaxf(acc[mi][ni][r] + bv, 0.f);
        }
    }
}

// ---------------- deconv1 v2 (fused upsample): 128x128 tile, fp16 single-pass ----------------
// M = 100352, N = 256. Grid (784, 2).
__global__ __launch_bounds__(256, 3) void deconv1_f16_v2(const _Float16* __restrict__ I,
                                                         const _Float16* __restrict__ WT,
                                                         const _Float16* __restrict__ zg,
                                                         const float* __restrict__ bias,
                                                         _Float16* __restrict__ out) {
    __shared__ __align__(16) _Float16 lds[16384];       // A 0, B 8192 (32 KiB)
    const int BO = 8192;
    const int t = threadIdx.x, lane = t & 63, w = t >> 6;
    const int wm = w >> 1, wn = w & 1;
    const int l16 = lane & 15, l4 = lane >> 4;
    const int m0 = blockIdx.x * 128, n0 = blockIdx.y * 128;
    const int rl = lane >> 3;
    const int chS = (((lane & 7) ^ rl)) << 3;
    int ay[4], ax[4], ab[4], wb[4], aoff[4];
    bool av[4];
#pragma unroll
    for (int j = 0; j < 4; ++j) {
        const int r = w * 32 + j * 8 + rl;
        const int gm = m0 + r;
        const int b = gm / 196, rem = gm % 196;
        ay[j] = rem / 14; ax[j] = rem % 14; ab[j] = b * 49;
        wb[j] = (n0 + r) << 8;
    }
    f32x4 acc[4][4] = {};

    for (int kt = 0; kt < 64; ++kt) {
        const int kk = kt >> 2;
        if ((kt & 3) == 0) {
            const int ky = kk >> 2, kx = kk & 3;
#pragma unroll
            for (int j = 0; j < 4; ++j) {
                const int iy = ay[j] + ky - 1, ix = ax[j] + kx - 1;
                av[j] = ((unsigned)iy < 14u) && ((unsigned)ix < 14u);
                aoff[j] = (ab[j] + (iy >> 1) * 7 + (ix >> 1)) << 8;
            }
        }
        const int kc = (kt & 3) << 6;
        __syncthreads();
#pragma unroll
        for (int j = 0; j < 4; ++j) {
            const int rowb = (w * 32 + j * 8) << 6;
            const _Float16* ga = av[j] ? (I + aoff[j] + kc + chS) : zg;
            gl_lds16(ga, lds + rowb);
            gl_lds16(WT + (kk << 16) + wb[j] + kc + chS, lds + BO + rowb);
        }
        __syncthreads();
#pragma unroll
        for (int ks = 0; ks < 2; ++ks) {
            half8 bf[4];
#pragma unroll
            for (int ni = 0; ni < 4; ++ni) {
                const int row = wn * 64 + ni * 16 + l16;
                const int p = (ks * 4 + l4) ^ (row & 7);
                bf[ni] = *(const half8*)&lds[BO + (row << 6) + (p << 3)];
            }
#pragma unroll
            for (int mi = 0; mi < 4; ++mi) {
                const int row = wm * 64 + mi * 16 + l16;
                const int p = (ks * 4 + l4) ^ (row & 7);
                const half8 af = *(const half8*)&lds[(row << 6) + (p << 3)];
#pragma unroll
                for (int ni = 0; ni < 4; ++ni)
                    acc[mi][ni] = __builtin_amdgcn_mfma_f32_16x16x32_f16(af, bf[ni], acc[mi][ni], 0, 0, 0);
            }
        }
    }
#pragma unroll
    for (int ni = 0; ni < 4; ++ni) {
        const int col = n0 + wn * 64 + ni * 16 + l16;
        const float bv = bias[col];
#pragma unroll
        for (int mi = 0; mi < 4; ++mi) {
            const int mrow = m0 + wm * 64 + mi * 16 + l4 * 4;
#pragma unroll
            for (int r = 0; r < 4; ++r)
                out[(size_t)(mrow + r) * 256 + col] = (_Float16)fmaxf(acc[mi][ni][r] + bv, 0.f);
        }
    }
}

// ---------------- maxpool 2x2 on h2 (f32) -> h2p (f32, flattened NHWC) ----------------
__global__ __launch_bounds__(256) void pool2_kernel(const float* __restrict__ h2, float* __restrict__ h2p) {
    int idx = blockIdx.x * 256 + threadIdx.x;           // 256*49*256
    int c = idx & 255;
    int rest = idx >> 8;
    int px = rest % 7, py = (rest / 7) % 7, b = rest / 49;
    const float* base = h2 + (((size_t)(b * 14 + 2 * py)) * 14 + 2 * px) * 256 + c;
    float v = fmaxf(fmaxf(base[0], base[256]), fmaxf(base[14 * 256], base[14 * 256 + 256]));
    h2p[idx] = v;
}

// ---------------- encoder linear: [256,12544] @ [12544,64] + b -> zcat rows 0..255 ----------------
__global__ __launch_bounds__(256) void enc_kernel(const float* __restrict__ h2p, const float* __restrict__ ew,
                                                  const float* __restrict__ eb, float* __restrict__ zcat) {
    __shared__ float arow[12544];
    __shared__ float part[256];
    const int b = blockIdx.x, t = threadIdx.x;
    const float* src = h2p + (size_t)b * 12544;
    for (int i = t; i < 12544; i += 256) arow[i] = src[i];
    __syncthreads();
    const int n = t & 63, chunk = t >> 6;
    float acc = 0.f;
    const int k0 = chunk * 3136;
    for (int k = k0; k < k0 + 3136; ++k) acc += arow[k] * ew[k * 64 + n];
    part[t] = acc;
    __syncthreads();
    if (t < 64) zcat[b * 64 + t] = part[t] + part[t + 64] + part[t + 128] + part[t + 192] + eb[t];
}

// ---------------- SOM: nearest embedding (argmin, first-index ties) -> zcat rows 256..511 ----------------
__global__ __launch_bounds__(256) void som_kernel(const float* __restrict__ emb, float* __restrict__ zcat) {
    __shared__ float zrow[64];
    __shared__ float sd[256];
    __shared__ int si[256];
    const int b = blockIdx.x, t = threadIdx.x;
    if (t < 64) zrow[t] = zcat[b * 64 + t];
    __syncthreads();
    float acc = 0.f;
    const float* e = emb + t * 64;
    for (int d = 0; d < 64; ++d) { float df = zrow[d] - e[d]; acc += df * df; }
    sd[t] = acc; si[t] = t;
    __syncthreads();
    for (int off = 128; off >= 1; off >>= 1) {
        if (t < off) {
            float d2 = sd[t + off]; int i2 = si[t + off];
            if (d2 < sd[t] || (d2 == sd[t] && i2 < si[t])) { sd[t] = d2; si[t] = i2; }
        }
        __syncthreads();
    }
    const int k = si[0];
    if (t < 64) zcat[(256 + b) * 64 + t] = emb[k * 64 + t];
}

// ---------------- decoder linear: [512,64] @ [64,12544] + b -> dech fp16 ----------------
__global__ __launch_bounds__(256) void dec_kernel(const float* __restrict__ zcat, const float* __restrict__ dw,
                                                  const float* __restrict__ db, _Float16* __restrict__ dech) {
    __shared__ float z[8][64];
    const int t = threadIdx.x;
    const int bg = blockIdx.x / 49;                     // group of 8 batch rows
    const int nc = blockIdx.x % 49;
    for (int i = t; i < 512; i += 256) z[i >> 6][i & 63] = zcat[bg * 512 + i];
    __syncthreads();
    const int n = nc * 256 + t;
    const float bv = db[n];
    float acc[8];
#pragma unroll
    for (int j = 0; j < 8; ++j) acc[j] = bv;
    for (int k = 0; k < 64; ++k) {
        float wv = dw[(size_t)k * 12544 + n];
#pragma unroll
        for (int j = 0; j < 8; ++j) acc[j] += z[j][k] * wv;
    }
#pragma unroll
    for (int j = 0; j < 8; ++j) dech[((size_t)(bg * 8 + j)) * 12544 + n] = (_Float16)acc[j];
}

// ---------------- deconv2 v2: 4x4 output tile per block, LDS-staged input, fdot2 ----------------
__global__ __launch_bounds__(256) void deconv2_v2(const _Float16* __restrict__ d1, const _Float16* __restrict__ w,
                                                  const float* __restrict__ bias, float* __restrict__ out) {
    __shared__ _Float16 ds[6400];                       // 5x5x256 input patch
    __shared__ _Float16 wl[4096];
    const int t = threadIdx.x;
    const int blk = blockIdx.x;                         // 512*49
    const int tile = blk % 49, b = blk / 49;
    const int ty = tile / 7, tx = tile % 7;
    const int iy0 = 2 * ty - 1, ix0 = 2 * tx - 1;
    for (int i = t; i < 1024; i += 256)
        *(half4*)&wl[i * 4] = *(const half4*)&w[i * 4];
    const half4 z4 = {};
    for (int i = t; i < 1600; i += 256) {               // 1600 half4 units of the 5x5 patch
        const int pix = i >> 6, c4 = (i & 63) << 2;
        const int py = pix / 5, px = pix % 5;
        const int iy = iy0 + py, ix = ix0 + px;
        half4 v = z4;
        if ((unsigned)iy < 14u && (unsigned)ix < 14u)
            v = *(const half4*)&d1[(((size_t)(b * 14 + iy)) * 14 + ix) * 256 + c4];
        *(half4*)&ds[pix * 256 + c4] = v;
    }
    __syncthreads();
    const int wv = t >> 6, lane = t & 63;
    const int ci0 = lane * 4;
    const float bv = bias[0];
#pragma unroll
    for (int pp = 0; pp < 4; ++pp) {
        const int p = wv + pp * 4;                      // 16 pixels
        const int oy = ty * 4 + (p >> 2), ox = tx * 4 + (p & 3);
        float acc = 0.f;
#pragma unroll
        for (int kk = 0; kk < 16; ++kk) {
            const int ky = kk >> 2, kx = kk & 3;
            const int iy = oy + ky - 1, ix = ox + kx - 1;
            if ((unsigned)iy < 28u && (unsigned)ix < 28u) {
                const int lp = ((iy >> 1) - iy0) * 5 + ((ix >> 1) - ix0);
                const half4 dv = *(const half4*)&ds[lp * 256 + ci0];
                const half4 wv4 = *(const half4*)&wl[kk * 256 + ci0];
                half2v dlo = {dv.x, dv.y}, dhi = {dv.z, dv.w};
                half2v wlo = {wv4.x, wv4.y}, whi = {wv4.z, wv4.w};
                acc = __builtin_amdgcn_fdot2(dlo, wlo, acc, false);
                acc = __builtin_amdgcn_fdot2(dhi, whi, acc, false);
            }
        }
#pragma unroll
        for (int off = 32; off; off >>= 1) acc += __shfl_xor(acc, off);
        if (lane == 0) out[(size_t)b * 784 + oy * 28 + ox] = 1.f / (1.f + expf(-(acc + bv)));
    }
}

extern "C" void kernel_launch(void* const* d_in, const int* in_sizes, int n_in,
                              void* d_out, int out_size, void* d_ws, size_t ws_size,
                              hipStream_t stream) {
    const float* x    = (const float*)d_in[0];
    const float* c1w  = (const float*)d_in[1];
    const float* c1b  = (const float*)d_in[2];
    const float* c2w  = (const float*)d_in[3];
    const float* c2b  = (const float*)d_in[4];
    const float* ew   = (const float*)d_in[5];
    const float* eb   = (const float*)d_in[6];
    const float* emb  = (const float*)d_in[7];
    const float* dw   = (const float*)d_in[8];
    const float* db   = (const float*)d_in[9];
    const float* dc1w = (const float*)d_in[10];
    const float* dc1b = (const float*)d_in[11];
    const float* dc2w = (const float*)d_in[12];
    const float* dc2b = (const float*)d_in[13];
    float* out = (float*)d_out;

    char* ws = (char*)d_ws;
    size_t off = 0;
    auto alloc = [&](size_t bytes) { size_t o = off; off += (bytes + 255) & ~(size_t)255; return o; };

    u16*      h1p_hi = (u16*)(ws + alloc((size_t)256 * 196 * 256 * 2));
    u16*      h1p_lo = (u16*)(ws + alloc((size_t)256 * 196 * 256 * 2));
    u16*      w2T_hi = (u16*)(ws + alloc((size_t)16 * 256 * 256 * 2));
    u16*      w2T_lo = (u16*)(ws + alloc((size_t)16 * 256 * 256 * 2));
    float*    h2     = (float*)(ws + alloc((size_t)256 * 196 * 256 * 4));
    float*    h2p    = (float*)(ws + alloc((size_t)256 * 49 * 256 * 4));
    float*    zcat   = (float*)(ws + alloc((size_t)512 * 64 * 4));
    _Float16* dech   = (_Float16*)(ws + alloc((size_t)512 * 49 * 256 * 2));
    _Float16* dw1T   = (_Float16*)(ws + alloc((size_t)16 * 256 * 256 * 2));
    _Float16* d1     = (_Float16*)(ws + alloc((size_t)512 * 196 * 256 * 2));
    _Float16* w2h    = (_Float16*)(ws + alloc((size_t)4096 * 2));
    u16*      zg     = (u16*)(ws + alloc(256));

    hipMemsetAsync(zg, 0, 256, stream);
    wprep_split_kernel<<<4096, 256, 0, stream>>>(c2w, w2T_hi, w2T_lo);
    wprep_f16_kernel<<<4096, 256, 0, stream>>>(dc1w, dw1T);
    wprep_c2_kernel<<<16, 256, 0, stream>>>(dc2w, w2h);
    conv1_pool_kernel<<<50176, 256, 0, stream>>>(x, c1w, c1b, h1p_hi, h1p_lo);
    conv2_split_v2<<<dim3(392, 2), 256, 0, stream>>>(h1p_hi, h1p_lo, w2T_hi, w2T_lo, zg, c2b, h2);
    pool2_kernel<<<12544, 256, 0, stream>>>(h2, h2p);
    enc_kernel<<<256, 256, 0, stream>>>(h2p, ew, eb, zcat);
    som_kernel<<<256, 256, 0, stream>>>(emb, zcat);
    dec_kernel<<<3136, 256, 0, stream>>>(zcat, dw, db, dech);
    deconv1_f16_v2<<<dim3(784, 2), 256, 0, stream>>>(dech, dw1T, (const _Float16*)zg, dc1b, d1);
    deconv2_v2<<<25088, 256, 0, stream>>>(d1, w2h, dc2b, out);
}

// Round 3
// 841.029 us; speedup vs baseline: 1.9697x; 1.0597x over previous
//
#include <hip/hip_runtime.h>
#include <hip/hip_bf16.h>

typedef unsigned short u16;
using short8 = __attribute__((ext_vector_type(8))) short;
using half8  = __attribute__((ext_vector_type(8))) _Float16;
using half4  = __attribute__((ext_vector_type(4))) _Float16;
using half2v = __attribute__((ext_vector_type(2))) _Float16;
using f32x4  = __attribute__((ext_vector_type(4))) float;

__device__ __forceinline__ u16 f2bf(float f) {
    unsigned int u = __float_as_uint(f);
    u += 0x7FFFu + ((u >> 16) & 1u);   // RNE
    return (u16)(u >> 16);
}
__device__ __forceinline__ float bf2f(u16 h) {
    return __uint_as_float(((unsigned int)h) << 16);
}

__device__ __forceinline__ void gl_lds16(const void* g, void* l) {
    __builtin_amdgcn_global_load_lds((const __attribute__((address_space(1))) void*)g,
                                     (__attribute__((address_space(3))) void*)l, 16, 0, 0);
}

#define PIPE_WAIT8() asm volatile("s_waitcnt vmcnt(8)" ::: "memory")
#define PIPE_WAIT0() asm volatile("s_waitcnt vmcnt(0)" ::: "memory")
#define BAR() __builtin_amdgcn_s_barrier()

// ---------------- weight prep: conv2 HWIO -> [kk][n][ci], split bf16 hi/lo ----------------
__global__ __launch_bounds__(256) void wprep_split_kernel(const float* __restrict__ src,
                                                          u16* __restrict__ hi, u16* __restrict__ lo) {
    int idx = blockIdx.x * 256 + threadIdx.x;          // 16*256*256
    int ci = idx & 255, n = (idx >> 8) & 255, kk = idx >> 16;
    float v = src[(kk * 256 + ci) * 256 + n];
    u16 h = f2bf(v);
    hi[idx] = h;
    lo[idx] = f2bf(v - bf2f(h));
}

// ---------------- weight prep: deconv1 parity-combined -> [tap_g][n][ci] fp16 (25 taps) ----------------
__global__ __launch_bounds__(256) void wprep_dc1_par(const float* __restrict__ src, _Float16* __restrict__ dst) {
    const int idx = blockIdx.x * 256 + threadIdx.x;    // 25*65536
    const int ci = idx & 255, n = (idx >> 8) & 255, tg = idx >> 16;
    int p, j;
    if (tg < 9)       { p = 0; j = tg; }
    else if (tg < 15) { p = 1; j = tg - 9; }
    else if (tg < 21) { p = 2; j = tg - 15; }
    else              { p = 3; j = tg - 21; }
    const int dy = p >> 1, dx = p & 1;
    const int nx = 3 - dx;
    const int oyi = j / nx, oxi = j % nx;
    int ky0, kyn, kx0, kxn;
    if (dy == 0) { ky0 = (oyi == 0) ? 0 : (oyi == 1 ? 1 : 3); kyn = (oyi == 1) ? 2 : 1; }
    else         { ky0 = (oyi == 0) ? 0 : 2;                  kyn = 2; }
    if (dx == 0) { kx0 = (oxi == 0) ? 0 : (oxi == 1 ? 1 : 3); kxn = (oxi == 1) ? 2 : 1; }
    else         { kx0 = (oxi == 0) ? 0 : 2;                  kxn = 2; }
    float s = 0.f;
    for (int a = 0; a < kyn; ++a)
        for (int c = 0; c < kxn; ++c)
            s += src[(((ky0 + a) * 4 + (kx0 + c)) * 256 + ci) * 256 + n];
    dst[((size_t)tg << 16) + (n << 8) + ci] = (_Float16)s;
}

// ---------------- weight prep: deconv2 parity-combined -> [p][9][256] fp16 (zero-padded taps) ----------------
__global__ __launch_bounds__(256) void wprep_dc2_par(const float* __restrict__ src, _Float16* __restrict__ dst) {
    const int idx = blockIdx.x * 256 + threadIdx.x;    // 36*256 = 9216
    if (idx >= 9216) return;
    const int ci = idx & 255;
    const int j9 = (idx >> 8) % 9, p = (idx >> 8) / 9;
    const int dy = p >> 1, dx = p & 1;
    const int oyi = j9 / 3, oxi = j9 % 3;
    float s = 0.f;
    if (!((dy == 1 && oyi == 2) || (dx == 1 && oxi == 2))) {
        int ky0, kyn, kx0, kxn;
        if (dy == 0) { ky0 = (oyi == 0) ? 0 : (oyi == 1 ? 1 : 3); kyn = (oyi == 1) ? 2 : 1; }
        else         { ky0 = (oyi == 0) ? 0 : 2;                  kyn = 2; }
        if (dx == 0) { kx0 = (oxi == 0) ? 0 : (oxi == 1 ? 1 : 3); kxn = (oxi == 1) ? 2 : 1; }
        else         { kx0 = (oxi == 0) ? 0 : 2;                  kxn = 2; }
        for (int a = 0; a < kyn; ++a)
            for (int c = 0; c < kxn; ++c)
                s += src[((ky0 + a) * 4 + (kx0 + c)) * 256 + ci];
    }
    dst[idx] = (_Float16)s;
}

// ---------------- conv1 (1->256) + ReLU + maxpool, block = (b, pooled row) ----------------
__global__ __launch_bounds__(256) void conv1_pool_v2(const float* __restrict__ x,
                                                     const float* __restrict__ w,
                                                     const float* __restrict__ bias,
                                                     u16* __restrict__ hi, u16* __restrict__ lo) {
    __shared__ float xs[5][32];                         // cols: x-col = c-1, zero-padded
    const int blk = blockIdx.x;                         // b*14 + py
    const int py = blk % 14, b = blk / 14;
    const int t = threadIdx.x;
    for (int i = t; i < 160; i += 256) {
        const int r = i >> 5, c = i & 31;
        const int gy = 2 * py - 1 + r, gx = c - 1;
        float v = 0.f;
        if ((unsigned)gy < 28u && (unsigned)gx < 28u) v = x[(b * 28 + gy) * 28 + gx];
        xs[r][c] = v;
    }
    __syncthreads();
    float wr[16];
#pragma unroll
    for (int k = 0; k < 16; ++k) wr[k] = w[k * 256 + t];
    const float bs = bias[t];
    for (int px = 0; px < 14; ++px) {
        float m = 0.f;
#pragma unroll
        for (int dy = 0; dy < 2; ++dy)
#pragma unroll
            for (int dx = 0; dx < 2; ++dx) {
                float a = bs;
#pragma unroll
                for (int ky = 0; ky < 4; ++ky)
#pragma unroll
                    for (int kx = 0; kx < 4; ++kx)
                        a += xs[dy + ky][2 * px + dx + kx] * wr[ky * 4 + kx];
                m = fmaxf(m, a);
            }
        u16 h = f2bf(m);
        const int o = ((b * 14 + py) * 14 + px) * 256 + t;
        hi[o] = h;
        lo[o] = f2bf(m - bf2f(h));
    }
}

// ---------------- conv2 v3: 128x128 tile, 2-buffer counted-vmcnt pipeline, split-bf16 3-pass ----------------
// M = 50176, N = 256, K = 16 x 256. Grid (392, 2). LDS rows: [hi 64B | lo 64B] = 128B, XOR(row&7) chunk swizzle.
__global__ __launch_bounds__(256, 2) void conv2_split_v3(const u16* __restrict__ Ih, const u16* __restrict__ Il,
                                                         const u16* __restrict__ Wh, const u16* __restrict__ Wl,
                                                         const u16* __restrict__ zg,
                                                         const float* __restrict__ bias, float* __restrict__ out) {
    __shared__ __align__(16) short lds[32768];          // 64KB: 2 bufs x (A 8192 | B 8192) shorts
    const int t = threadIdx.x, lane = t & 63, w = t >> 6;
    const int wm = w >> 1, wn = w & 1;
    const int l16 = lane & 15, l4 = lane >> 4;
    const int m0 = blockIdx.x * 128, n0 = blockIdx.y * 128;

    const int rl8 = lane >> 3;
    const int g = (lane & 7) ^ rl8;                     // global chunk: 0-3 hi, 4-7 lo
    const u16* selA = (g < 4 ? Ih : Il) + ((g & 3) << 3);
    const u16* selB = (g < 4 ? Wh : Wl) + ((g & 3) << 3);

    int ay[4], ax[4], ab[4], wb[4];
#pragma unroll
    for (int j = 0; j < 4; ++j) {
        const int r = w * 32 + j * 8 + rl8;
        const int gm = m0 + r;
        const int b = gm / 196, rem = gm % 196;
        ay[j] = rem / 14; ax[j] = rem % 14; ab[j] = b * 196;
        wb[j] = (n0 + r) << 8;
    }
    int aoff[4]; bool av[4];
    auto dectap = [&](int kk) {
        const int ky = kk >> 2, kx = kk & 3;
#pragma unroll
        for (int j = 0; j < 4; ++j) {
            const int iy = ay[j] + ky - 1, ix = ax[j] + kx - 1;
            av[j] = ((unsigned)iy < 14u) && ((unsigned)ix < 14u);
            aoff[j] = (ab[j] + iy * 14 + ix) << 8;
        }
    };
    int rdA[4], rdB[4];
#pragma unroll
    for (int mi = 0; mi < 4; ++mi) {
        const int ra = wm * 64 + mi * 16 + l16;
        rdA[mi] = (ra << 6) + ((l4 ^ (ra & 7)) << 3);
    }
#pragma unroll
    for (int ni = 0; ni < 4; ++ni) {
        const int rb = wn * 64 + ni * 16 + l16;
        rdB[ni] = 8192 + (rb << 6) + ((l4 ^ (rb & 7)) << 3);
    }
    auto stage = [&](int h) {
        const int kk = h >> 3, kc = (h & 7) << 5;
        const int buf = (h & 1) << 14;
#pragma unroll
        for (int j = 0; j < 4; ++j) {
            const int rowb = buf + ((w * 32 + j * 8) << 6);
            const u16* asrc = av[j] ? (selA + aoff[j] + kc) : zg;
            gl_lds16(asrc, lds + rowb);
            gl_lds16(selB + (kk << 16) + wb[j] + kc, lds + 8192 + rowb);
        }
    };

    f32x4 acc[4][4] = {};
    dectap(0);
    stage(0);
    for (int h = 0; h < 128; ++h) {
        const int hn = (h < 127) ? h + 1 : 127;
        if ((hn & 7) == 0) dectap(hn >> 3);
        stage(hn);
        PIPE_WAIT8();
        BAR();
        const int base = (h & 1) << 14;
        short8 bh8[4], bl8[4];
#pragma unroll
        for (int ni = 0; ni < 4; ++ni) {
            bh8[ni] = *(const short8*)&lds[base + rdB[ni]];
            bl8[ni] = *(const short8*)&lds[base + (rdB[ni] ^ 32)];
        }
#pragma unroll
        for (int mi = 0; mi < 4; ++mi) {
            const short8 ah = *(const short8*)&lds[base + rdA[mi]];
            const short8 al = *(const short8*)&lds[base + (rdA[mi] ^ 32)];
#pragma unroll
            for (int ni = 0; ni < 4; ++ni) {
                acc[mi][ni] = __builtin_amdgcn_mfma_f32_16x16x32_bf16(ah, bh8[ni], acc[mi][ni], 0, 0, 0);
                acc[mi][ni] = __builtin_amdgcn_mfma_f32_16x16x32_bf16(ah, bl8[ni], acc[mi][ni], 0, 0, 0);
                acc[mi][ni] = __builtin_amdgcn_mfma_f32_16x16x32_bf16(al, bh8[ni], acc[mi][ni], 0, 0, 0);
            }
        }
        BAR();
    }
    PIPE_WAIT0();
#pragma unroll
    for (int ni = 0; ni < 4; ++ni) {
        const int col = n0 + wn * 64 + ni * 16 + l16;
        const float bv = bias[col];
#pragma unroll
        for (int mi = 0; mi < 4; ++mi) {
            const int mrow = m0 + wm * 64 + mi * 16 + l4 * 4;
#pragma unroll
            for (int r = 0; r < 4; ++r)
                out[(size_t)(mrow + r) * 256 + col] = fmaxf(acc[mi][ni][r] + bv, 0.f);
        }
    }
}

// ---------------- deconv1 parity GEMM: M=25088, N=256, K=ntaps(p)x256; fp16 pipeline ----------------
// Grid (196, 2, 4). Output written to upsampled 14x14 grid position (2Y+dy, 2X+dx).
__global__ __launch_bounds__(256, 2) void deconv1_par(const _Float16* __restrict__ I,
                                                      const _Float16* __restrict__ WC,
                                                      const _Float16* __restrict__ zg,
                                                      const float* __restrict__ bias,
                                                      _Float16* __restrict__ out) {
    __shared__ __align__(16) _Float16 lds[32768];       // 64KB: 2 bufs x (A 8192 | B 8192) halfs
    const int t = threadIdx.x, lane = t & 63, w = t >> 6;
    const int wm = w >> 1, wn = w & 1;
    const int l16 = lane & 15, l4 = lane >> 4;
    const int m0 = blockIdx.x * 128, n0 = blockIdx.y * 128;
    const int p = blockIdx.z, dy = p >> 1, dx = p & 1;
    const int nx = 3 - dx;
    const int ntaps = (3 - dy) * nx;
    const int pbase = (dy == 0) ? (dx == 0 ? 0 : 9) : (dx == 0 ? 15 : 21);
    const int nkt = ntaps * 4;

    const int rl8 = lane >> 3;
    const int g = (lane & 7) ^ rl8;
    const _Float16* selA = I + (g << 3);
    const _Float16* selB = WC + ((size_t)pbase << 16) + (g << 3);

    int aY[4], aX[4], ab[4], wb[4];
#pragma unroll
    for (int j = 0; j < 4; ++j) {
        const int r = w * 32 + j * 8 + rl8;
        const int gm = m0 + r;
        const int b = gm / 49, rem = gm % 49;
        aY[j] = rem / 7; aX[j] = rem % 7; ab[j] = b * 49;
        wb[j] = (n0 + r) << 8;
    }
    int aoff[4]; bool av[4];
    auto dectap = [&](int kk) {
        const int oy = kk / nx - (dy == 0 ? 1 : 0);
        const int ox = kk % nx - (dx == 0 ? 1 : 0);
#pragma unroll
        for (int j = 0; j < 4; ++j) {
            const int iy = aY[j] + oy, ix = aX[j] + ox;
            av[j] = ((unsigned)iy < 7u) && ((unsigned)ix < 7u);
            aoff[j] = (ab[j] + iy * 7 + ix) << 8;
        }
    };
    int rdA[4], rdB[4];
#pragma unroll
    for (int mi = 0; mi < 4; ++mi) {
        const int ra = wm * 64 + mi * 16 + l16;
        rdA[mi] = (ra << 6) + ((l4 ^ (ra & 7)) << 3);
    }
#pragma unroll
    for (int ni = 0; ni < 4; ++ni) {
        const int rb = wn * 64 + ni * 16 + l16;
        rdB[ni] = 8192 + (rb << 6) + ((l4 ^ (rb & 7)) << 3);
    }
    auto stage = [&](int kt) {
        const int kk = kt >> 2, kc = (kt & 3) << 6;
        const int buf = (kt & 1) << 14;
#pragma unroll
        for (int j = 0; j < 4; ++j) {
            const int rowb = buf + ((w * 32 + j * 8) << 6);
            const _Float16* asrc = av[j] ? (selA + aoff[j] + kc) : zg;
            gl_lds16(asrc, lds + rowb);
            gl_lds16(selB + (kk << 16) + wb[j] + kc, lds + 8192 + rowb);
        }
    };

    f32x4 acc[4][4] = {};
    dectap(0);
    stage(0);
    for (int kt = 0; kt < nkt; ++kt) {
        const int ktn = (kt < nkt - 1) ? kt + 1 : kt;
        if ((ktn & 3) == 0 && ktn == kt + 1) dectap(ktn >> 2);
        stage(ktn);
        PIPE_WAIT8();
        BAR();
        const int base = (kt & 1) << 14;
#pragma unroll
        for (int ks = 0; ks < 2; ++ks) {
            const int x32 = ks << 5;
            half8 b8[4];
#pragma unroll
            for (int ni = 0; ni < 4; ++ni)
                b8[ni] = *(const half8*)&lds[base + (rdB[ni] ^ x32)];
#pragma unroll
            for (int mi = 0; mi < 4; ++mi) {
                const half8 a8 = *(const half8*)&lds[base + (rdA[mi] ^ x32)];
#pragma unroll
                for (int ni = 0; ni < 4; ++ni)
                    acc[mi][ni] = __builtin_amdgcn_mfma_f32_16x16x32_f16(a8, b8[ni], acc[mi][ni], 0, 0, 0);
            }
        }
        BAR();
    }
    PIPE_WAIT0();
#pragma unroll
    for (int mi = 0; mi < 4; ++mi) {
        const int mb = m0 + wm * 64 + mi * 16 + l4 * 4;
#pragma unroll
        for (int r = 0; r < 4; ++r) {
            const int m = mb + r;
            const int b = m / 49, rem = m % 49;
            const int Y = rem / 7, X = rem % 7;
            _Float16* op = out + (((size_t)(b * 196 + (2 * Y + dy) * 14 + (2 * X + dx))) << 8);
#pragma unroll
            for (int ni = 0; ni < 4; ++ni) {
                const int col = n0 + wn * 64 + ni * 16 + l16;
                op[col] = (_Float16)fmaxf(acc[mi][ni][r] + bias[col], 0.f);
            }
        }
    }
}

// ---------------- maxpool 2x2 on h2 (f32) -> h2p ----------------
__global__ __launch_bounds__(256) void pool2_kernel(const float* __restrict__ h2, float* __restrict__ h2p) {
    int idx = blockIdx.x * 256 + threadIdx.x;           // 256*49*256
    int c = idx & 255;
    int rest = idx >> 8;
    int px = rest % 7, py = (rest / 7) % 7, b = rest / 49;
    const float* base = h2 + (((size_t)(b * 14 + 2 * py)) * 14 + 2 * px) * 256 + c;
    float v = fmaxf(fmaxf(base[0], base[256]), fmaxf(base[14 * 256], base[14 * 256 + 256]));
    h2p[idx] = v;
}

// ---------------- encoder linear ----------------
__global__ __launch_bounds__(256) void enc_kernel(const float* __restrict__ h2p, const float* __restrict__ ew,
                                                  const float* __restrict__ eb, float* __restrict__ zcat) {
    __shared__ float arow[12544];
    __shared__ float part[256];
    const int b = blockIdx.x, t = threadIdx.x;
    const float* src = h2p + (size_t)b * 12544;
    for (int i = t; i < 12544; i += 256) arow[i] = src[i];
    __syncthreads();
    const int n = t & 63, chunk = t >> 6;
    float acc = 0.f;
    const int k0 = chunk * 3136;
    for (int k = k0; k < k0 + 3136; ++k) acc += arow[k] * ew[k * 64 + n];
    part[t] = acc;
    __syncthreads();
    if (t < 64) zcat[b * 64 + t] = part[t] + part[t + 64] + part[t + 128] + part[t + 192] + eb[t];
}

// ---------------- SOM argmin ----------------
__global__ __launch_bounds__(256) void som_kernel(const float* __restrict__ emb, float* __restrict__ zcat) {
    __shared__ float zrow[64];
    __shared__ float sd[256];
    __shared__ int si[256];
    const int b = blockIdx.x, t = threadIdx.x;
    if (t < 64) zrow[t] = zcat[b * 64 + t];
    __syncthreads();
    float acc = 0.f;
    const float* e = emb + t * 64;
    for (int d = 0; d < 64; ++d) { float df = zrow[d] - e[d]; acc += df * df; }
    sd[t] = acc; si[t] = t;
    __syncthreads();
    for (int off = 128; off >= 1; off >>= 1) {
        if (t < off) {
            float d2 = sd[t + off]; int i2 = si[t + off];
            if (d2 < sd[t] || (d2 == sd[t] && i2 < si[t])) { sd[t] = d2; si[t] = i2; }
        }
        __syncthreads();
    }
    const int k = si[0];
    if (t < 64) zcat[(256 + b) * 64 + t] = emb[k * 64 + t];
}

// ---------------- decoder linear ----------------
__global__ __launch_bounds__(256) void dec_kernel(const float* __restrict__ zcat, const float* __restrict__ dw,
                                                  const float* __restrict__ db, _Float16* __restrict__ dech) {
    __shared__ float z[8][64];
    const int t = threadIdx.x;
    const int bg = blockIdx.x / 49;
    const int nc = blockIdx.x % 49;
    for (int i = t; i < 512; i += 256) z[i >> 6][i & 63] = zcat[bg * 512 + i];
    __syncthreads();
    const int n = nc * 256 + t;
    const float bv = db[n];
    float acc[8];
#pragma unroll
    for (int j = 0; j < 8; ++j) acc[j] = bv;
    for (int k = 0; k < 64; ++k) {
        float wv = dw[(size_t)k * 12544 + n];
#pragma unroll
        for (int j = 0; j < 8; ++j) acc[j] += z[j][k] * wv;
    }
#pragma unroll
    for (int j = 0; j < 8; ++j) dech[((size_t)(bg * 8 + j)) * 12544 + n] = (_Float16)acc[j];
}

// ---------------- deconv2 v3: parity-combined 9-tap, LDS-staged patch, fdot2, sigmoid ----------------
__global__ __launch_bounds__(256) void deconv2_v3(const _Float16* __restrict__ d1, const _Float16* __restrict__ w2c,
                                                  const float* __restrict__ bias, float* __restrict__ out) {
    __shared__ _Float16 ds[6400];                       // 5x5x256 input patch
    __shared__ _Float16 wl[9216];                       // [2][2][9][256]
    const int t = threadIdx.x;
    const int blk = blockIdx.x;                         // 512*49
    const int tile = blk % 49, b = blk / 49;
    const int ty = tile / 7, tx = tile % 7;
    const int iy0 = 2 * ty - 1, ix0 = 2 * tx - 1;
    for (int i = t; i < 2304; i += 256)
        *(half4*)&wl[i * 4] = *(const half4*)&w2c[i * 4];
    const half4 z4 = {};
    for (int i = t; i < 1600; i += 256) {
        const int pix = i >> 6, c4 = (i & 63) << 2;
        const int py = pix / 5, px = pix % 5;
        const int iy = iy0 + py, ix = ix0 + px;
        half4 v = z4;
        if ((unsigned)iy < 14u && (unsigned)ix < 14u)
            v = *(const half4*)&d1[(((size_t)(b * 14 + iy)) * 14 + ix) * 256 + c4];
        *(half4*)&ds[pix * 256 + c4] = v;
    }
    __syncthreads();
    const int wv = t >> 6, lane = t & 63;
    const int ci0 = lane * 4;
    const float bv = bias[0];
#pragma unroll
    for (int pp = 0; pp < 4; ++pp) {
        const int pq = wv + pp * 4;                     // 16 pixels of the 4x4 tile
        const int oy = ty * 4 + (pq >> 2), ox = tx * 4 + (pq & 3);
        const int dy = oy & 1, Y = oy >> 1;
        const int dxp = ox & 1, X = ox >> 1;
        const _Float16* wbase = wl + ((dy * 2 + dxp) * 9) * 256 + ci0;
        float acc = 0.f;
#pragma unroll
        for (int j = 0; j < 9; ++j) {
            const int oyi = j / 3, oxi = j % 3;
            const int iy = Y + oyi - (dy == 0 ? 1 : 0);
            const int ix = X + oxi - (dxp == 0 ? 1 : 0);
            const int lp = (iy - iy0) * 5 + (ix - ix0);
            const half4 dv = *(const half4*)&ds[lp * 256 + ci0];
            const half4 wv4 = *(const half4*)&wbase[j * 256];
            half2v dlo = {dv.x, dv.y}, dhi = {dv.z, dv.w};
            half2v wlo = {wv4.x, wv4.y}, whi = {wv4.z, wv4.w};
            acc = __builtin_amdgcn_fdot2(dlo, wlo, acc, false);
            acc = __builtin_amdgcn_fdot2(dhi, whi, acc, false);
        }
#pragma unroll
        for (int off = 32; off; off >>= 1) acc += __shfl_xor(acc, off);
        if (lane == 0) out[(size_t)b * 784 + oy * 28 + ox] = 1.f / (1.f + expf(-(acc + bv)));
    }
}

extern "C" void kernel_launch(void* const* d_in, const int* in_sizes, int n_in,
                              void* d_out, int out_size, void* d_ws, size_t ws_size,
                              hipStream_t stream) {
    const float* x    = (const float*)d_in[0];
    const float* c1w  = (const float*)d_in[1];
    const float* c1b  = (const float*)d_in[2];
    const float* c2w  = (const float*)d_in[3];
    const float* c2b  = (const float*)d_in[4];
    const float* ew   = (const float*)d_in[5];
    const float* eb   = (const float*)d_in[6];
    const float* emb  = (const float*)d_in[7];
    const float* dw   = (const float*)d_in[8];
    const float* db   = (const float*)d_in[9];
    const float* dc1w = (const float*)d_in[10];
    const float* dc1b = (const float*)d_in[11];
    const float* dc2w = (const float*)d_in[12];
    const float* dc2b = (const float*)d_in[13];
    float* out = (float*)d_out;

    char* ws = (char*)d_ws;
    size_t off = 0;
    auto alloc = [&](size_t bytes) { size_t o = off; off += (bytes + 255) & ~(size_t)255; return o; };

    u16*      h1p_hi = (u16*)(ws + alloc((size_t)256 * 196 * 256 * 2));
    u16*      h1p_lo = (u16*)(ws + alloc((size_t)256 * 196 * 256 * 2));
    u16*      w2T_hi = (u16*)(ws + alloc((size_t)16 * 256 * 256 * 2));
    u16*      w2T_lo = (u16*)(ws + alloc((size_t)16 * 256 * 256 * 2));
    float*    h2     = (float*)(ws + alloc((size_t)256 * 196 * 256 * 4));
    float*    h2p    = (float*)(ws + alloc((size_t)256 * 49 * 256 * 4));
    float*    zcat   = (float*)(ws + alloc((size_t)512 * 64 * 4));
    _Float16* dech   = (_Float16*)(ws + alloc((size_t)512 * 49 * 256 * 2));
    _Float16* wc1    = (_Float16*)(ws + alloc((size_t)25 * 256 * 256 * 2));
    _Float16* d1     = (_Float16*)(ws + alloc((size_t)512 * 196 * 256 * 2));
    _Float16* w2c    = (_Float16*)(ws + alloc((size_t)9216 * 2));
    u16*      zg     = (u16*)(ws + alloc(256));

    hipMemsetAsync(zg, 0, 256, stream);
    wprep_split_kernel<<<4096, 256, 0, stream>>>(c2w, w2T_hi, w2T_lo);
    wprep_dc1_par<<<6400, 256, 0, stream>>>(dc1w, wc1);
    wprep_dc2_par<<<36, 256, 0, stream>>>(dc2w, w2c);
    conv1_pool_v2<<<3584, 256, 0, stream>>>(x, c1w, c1b, h1p_hi, h1p_lo);
    conv2_split_v3<<<dim3(392, 2), 256, 0, stream>>>(h1p_hi, h1p_lo, w2T_hi, w2T_lo, zg, c2b, h2);
    pool2_kernel<<<12544, 256, 0, stream>>>(h2, h2p);
    enc_kernel<<<256, 256, 0, stream>>>(h2p, ew, eb, zcat);
    som_kernel<<<256, 256, 0, stream>>>(emb, zcat);
    dec_kernel<<<3136, 256, 0, stream>>>(zcat, dw, db, dech);
    deconv1_par<<<dim3(196, 2, 4), 256, 0, stream>>>(dech, wc1, (const _Float16*)zg, dc1b, d1);
    deconv2_v3<<<25088, 256, 0, stream>>>(d1, w2c, dc2b, out);
}